// Round 2
// baseline (922.725 us; speedup 1.0000x reference)
//
#include <hip/hip_runtime.h>

#define NT    8192   // tokens
#define CIN   4096   // in_channel
#define COUT  4096   // out_channel
#define RK    16     // rank
#define ROWS  8      // tokens per block -> grid 1024 = 4 blocks/CU
#define CHUNK 256    // k per staged chunk
#define NCHUNK (CIN / CHUNK)   // 16
#define RST   36     // red row stride (floats): bank = 4*l -> 2-way = free

// ---------------------------------------------------------------------------
// Fused out = (x @ right^T) @ left^T + bias. One kernel, no workspace.
// grid = 1024 (8-token groups), 256 threads (4 waves), 4 blocks/CU.
// Phase 1 (lane = k-column): per chunk of 256 k, lane l owns k = l*4..l*4+3.
//   - x: NOT in LDS (zero reuse) -> global->reg, 1 KB/wave coalesced, 1-ahead
//     register prefetch (2 banks, static via unroll 2).
//   - rgt: LDS double-buffered [16][256] linear; rv read rs[r*256+l*4] =
//     64 lanes contiguous 1 KB -> conflict-free max-BW pattern.
//   - 16 ds_read_b128 + 128 FMA per chunk per thread (was 80 reads/chunk).
//   k is 64-way lane-split: one-time shfl_xor(32,16) + padded-LDS reduce
//   -> t[8][16] in tl.
// Phase 2: k2's verified body (lf regs, broadcast tl reads, float4 stores).
// LDS 33 KB -> 4 blocks/CU; __launch_bounds__(256,4) targets <=128 VGPR.
// ---------------------------------------------------------------------------
__global__ __launch_bounds__(256, 4) void fused(const float* __restrict__ x,
                                                const float* __restrict__ rgt,
                                                const float* __restrict__ lft,
                                                const float* __restrict__ bias,
                                                float* __restrict__ out)
{
    __shared__ __align__(16) float smem[8192];     // [2][4096] rgt dbuf; red aliases [0..2303]
    __shared__ __align__(16) float tl[ROWS * RK];  // t[8][16]

    const int tid = threadIdx.x;
    const int wv  = tid >> 6;
    const int l   = tid & 63;
    const int row0 = blockIdx.x * ROWS;

    // wave owns token rows {wv*2, wv*2+1}; lane owns k-cols l*4..l*4+3 per chunk
    const float* xr0 = x + (size_t)(row0 + wv * 2)     * CIN + l * 4;
    const float* xr1 = x + (size_t)(row0 + wv * 2 + 1) * CIN + l * 4;
    // staging: thread parks rgt rows {i*4+wv}, floats l*4..l*4+3
    const float* rbase = rgt + l * 4;

    float4 pfx[2][2];
    float4 pfr[4];
    float  acc[2][RK];
#pragma unroll
    for (int r = 0; r < RK; ++r) { acc[0][r] = 0.f; acc[1][r] = 0.f; }

    // ---- prologue: chunk 0 staged, chunk-0 x in regs
#pragma unroll
    for (int i = 0; i < 4; ++i)
        pfr[i] = *(const float4*)&rbase[(size_t)(i * 4 + wv) * CIN];
    pfx[0][0] = *(const float4*)&xr0[0];
    pfx[0][1] = *(const float4*)&xr1[0];
#pragma unroll
    for (int i = 0; i < 4; ++i)
        *(float4*)&smem[(i * 4 + wv) * CHUNK + l * 4] = pfr[i];
    __syncthreads();

#pragma unroll 2
    for (int c = 0; c < NCHUNK; ++c) {
        const int cb = c & 1, nb = (c + 1) & 1;
        // issue next chunk's loads at the TOP: full compute period in flight
        if (c + 1 < NCHUNK) {
            const int ko = (c + 1) * CHUNK;
#pragma unroll
            for (int i = 0; i < 4; ++i)
                pfr[i] = *(const float4*)&rbase[(size_t)(i * 4 + wv) * CIN + ko];
            pfx[nb][0] = *(const float4*)&xr0[ko];
            pfx[nb][1] = *(const float4*)&xr1[ko];
        }
        // compute chunk c: 16 contiguous b128 reads + 128 fmac
        const float* rsb = &smem[cb * 4096];
        const float4 xv0 = pfx[cb][0], xv1 = pfx[cb][1];
#pragma unroll
        for (int r = 0; r < RK; ++r) {
            const float4 rv = *(const float4*)&rsb[r * CHUNK + l * 4];
            acc[0][r] += rv.x * xv0.x; acc[0][r] += rv.y * xv0.y;
            acc[0][r] += rv.z * xv0.z; acc[0][r] += rv.w * xv0.w;
            acc[1][r] += rv.x * xv1.x; acc[1][r] += rv.y * xv1.y;
            acc[1][r] += rv.z * xv1.z; acc[1][r] += rv.w * xv1.w;
        }
        if (c + 1 < NCHUNK) {
            // park next chunk (waits only pfr's vmcnt), publish
#pragma unroll
            for (int i = 0; i < 4; ++i)
                *(float4*)&smem[nb * 4096 + (i * 4 + wv) * CHUNK + l * 4] = pfr[i];
            __syncthreads();
        }
    }

    // ---- k-reduce: 64 lanes -> 16 partials -> t[8][16]
#pragma unroll
    for (int rr = 0; rr < 2; ++rr)
#pragma unroll
        for (int r = 0; r < RK; ++r) {
            acc[rr][r] += __shfl_xor(acc[rr][r], 32);
            acc[rr][r] += __shfl_xor(acc[rr][r], 16);
        }
    // red aliases smem[0..2303] (buf0: last read at c=14, fenced by that sync;
    // c=15 compute read buf1 only)
    __syncthreads();
    if (l < 16) {
#pragma unroll
        for (int rr = 0; rr < 2; ++rr)
#pragma unroll
            for (int q = 0; q < 4; ++q)
                *(float4*)&smem[(wv * 16 + l) * RST + rr * 16 + q * 4] =
                    make_float4(acc[rr][q * 4 + 0], acc[rr][q * 4 + 1],
                                acc[rr][q * 4 + 2], acc[rr][q * 4 + 3]);
    }
    __syncthreads();
    if (tid < ROWS * RK) {
        const int row = tid >> 4, r = tid & 15;
        const int ws = row >> 1, rr = row & 1;
        float s = 0.f;
#pragma unroll
        for (int lp = 0; lp < 16; ++lp)
            s += smem[(ws * 16 + lp) * RST + rr * 16 + r];
        tl[row * RK + r] = s;
    }
    __syncthreads();

    // ---- phase 2: out[8][4096] = t @ left^T + bias, 4 column chunks
#pragma unroll 1
    for (int oc = 0; oc < 4; ++oc) {
        const int o0 = oc * 1024 + tid * 4;
        float4 lf[4][4];
#pragma unroll
        for (int oo = 0; oo < 4; ++oo)
#pragma unroll
            for (int q = 0; q < 4; ++q)
                lf[oo][q] = *(const float4*)&lft[(size_t)(o0 + oo) * RK + q * 4];
        const float4 bv = *(const float4*)&bias[o0];
        const float  bvf[4] = {bv.x, bv.y, bv.z, bv.w};

#pragma unroll
        for (int rr = 0; rr < ROWS; ++rr) {
            float4 ts[4];
#pragma unroll
            for (int q = 0; q < 4; ++q)
                ts[q] = ((const float4*)tl)[rr * 4 + q];   // uniform -> broadcast

            float res[4];
#pragma unroll
            for (int oo = 0; oo < 4; ++oo) {
                float a = bvf[oo];
#pragma unroll
                for (int q = 0; q < 4; ++q) {
                    a += lf[oo][q].x * ts[q].x;
                    a += lf[oo][q].y * ts[q].y;
                    a += lf[oo][q].z * ts[q].z;
                    a += lf[oo][q].w * ts[q].w;
                }
                res[oo] = a;
            }
            *(float4*)&out[(size_t)(row0 + rr) * COUT + o0] =
                make_float4(res[0], res[1], res[2], res[3]);
        }
    }
}

extern "C" void kernel_launch(void* const* d_in, const int* in_sizes, int n_in,
                              void* d_out, int out_size, void* d_ws, size_t ws_size,
                              hipStream_t stream)
{
    const float* x    = (const float*)d_in[0];
    const float* lft  = (const float*)d_in[1];   // [COUT][RK]
    const float* rgt  = (const float*)d_in[2];   // [RK][CIN]
    const float* bias = (const float*)d_in[3];
    float*       out  = (float*)d_out;

    (void)d_ws; (void)ws_size;                   // workspace unused (no poison fill)

    fused<<<dim3(NT / ROWS), dim3(256), 0, stream>>>(x, rgt, lft, bias, out);
}

// Round 3
// 368.872 us; speedup vs baseline: 2.5015x; 2.5015x over previous
//
#include <hip/hip_runtime.h>

#define NT    8192   // tokens
#define CIN   4096   // in_channel
#define COUT  4096   // out_channel
#define RK    16     // rank
#define ROWS  8      // tokens per block -> grid 1024
#define CHUNK 256    // k per staged chunk
#define NCHUNK (CIN / CHUNK)   // 16
#define RST   36     // red row stride (floats): bank = 4*l -> 2-way = free

// ---------------------------------------------------------------------------
// Fused out = (x @ right^T) @ left^T + bias. One kernel, no workspace.
// grid = 1024 (8-token groups), 256 threads (4 waves).
// Phase 1 (lane = k-column): per chunk of 256 k, lane l owns k = l*4..l*4+3.
//   - x: global->reg only (zero reuse), coalesced, 1-chunk-ahead prefetch.
//   - rgt: LDS double-buffered [16][256] linear; rv read rs[r*256+l*4] =
//     64 lanes contiguous 1 KB -> conflict-free (verified: conflicts == 0).
//   - 16 ds_read_b128 + 128 fmac per chunk per thread.
//   k is 64-way lane-split: shfl_xor(32,16) + padded-LDS reduce -> t[8][16].
// Phase 2: lf in regs, broadcast tl reads, float4 stores.
// NOTE: plain __launch_bounds__(256) — the (256,4) min-waves hint made the
// allocator clamp to 64 VGPRs and spill ~2.5 GB/launch to scratch (r2:
// FETCH 1.2 GB, WRITE 1.46 GB, 782 us). This footprint wants ~116 VGPRs
// = 4 waves/SIMD occupancy with zero spill (r1 evidence).
// ---------------------------------------------------------------------------
__global__ __launch_bounds__(256) void fused(const float* __restrict__ x,
                                             const float* __restrict__ rgt,
                                             const float* __restrict__ lft,
                                             const float* __restrict__ bias,
                                             float* __restrict__ out)
{
    __shared__ __align__(16) float smem[8192];     // [2][4096] rgt dbuf; red aliases [0..2303]
    __shared__ __align__(16) float tl[ROWS * RK];  // t[8][16]

    const int tid = threadIdx.x;
    const int wv  = tid >> 6;
    const int l   = tid & 63;
    const int row0 = blockIdx.x * ROWS;

    // wave owns token rows {wv*2, wv*2+1}; lane owns k-cols l*4..l*4+3 per chunk
    const float* xr0 = x + (size_t)(row0 + wv * 2)     * CIN + l * 4;
    const float* xr1 = x + (size_t)(row0 + wv * 2 + 1) * CIN + l * 4;
    // staging: thread parks rgt rows {i*4+wv}, floats l*4..l*4+3
    const float* rbase = rgt + l * 4;

    float4 pfx[2][2];
    float4 pfr[4];
    float  acc[2][RK];
#pragma unroll
    for (int r = 0; r < RK; ++r) { acc[0][r] = 0.f; acc[1][r] = 0.f; }

    // ---- prologue: chunk 0 staged, chunk-0 x in regs
#pragma unroll
    for (int i = 0; i < 4; ++i)
        pfr[i] = *(const float4*)&rbase[(size_t)(i * 4 + wv) * CIN];
    pfx[0][0] = *(const float4*)&xr0[0];
    pfx[0][1] = *(const float4*)&xr1[0];
#pragma unroll
    for (int i = 0; i < 4; ++i)
        *(float4*)&smem[(i * 4 + wv) * CHUNK + l * 4] = pfr[i];
    __syncthreads();

#pragma unroll 2
    for (int c = 0; c < NCHUNK; ++c) {
        const int cb = c & 1, nb = (c + 1) & 1;
        // issue next chunk's loads at the TOP: full compute period in flight
        if (c + 1 < NCHUNK) {
            const int ko = (c + 1) * CHUNK;
#pragma unroll
            for (int i = 0; i < 4; ++i)
                pfr[i] = *(const float4*)&rbase[(size_t)(i * 4 + wv) * CIN + ko];
            pfx[nb][0] = *(const float4*)&xr0[ko];
            pfx[nb][1] = *(const float4*)&xr1[ko];
        }
        // compute chunk c: 16 contiguous b128 reads + 128 fmac
        const float* rsb = &smem[cb * 4096];
        const float4 xv0 = pfx[cb][0], xv1 = pfx[cb][1];
#pragma unroll
        for (int r = 0; r < RK; ++r) {
            const float4 rv = *(const float4*)&rsb[r * CHUNK + l * 4];
            acc[0][r] += rv.x * xv0.x; acc[0][r] += rv.y * xv0.y;
            acc[0][r] += rv.z * xv0.z; acc[0][r] += rv.w * xv0.w;
            acc[1][r] += rv.x * xv1.x; acc[1][r] += rv.y * xv1.y;
            acc[1][r] += rv.z * xv1.z; acc[1][r] += rv.w * xv1.w;
        }
        if (c + 1 < NCHUNK) {
            // park next chunk (waits only pfr's vmcnt), publish
#pragma unroll
            for (int i = 0; i < 4; ++i)
                *(float4*)&smem[nb * 4096 + (i * 4 + wv) * CHUNK + l * 4] = pfr[i];
            __syncthreads();
        }
    }

    // ---- k-reduce: 64 lanes -> 16 partials -> t[8][16]
#pragma unroll
    for (int rr = 0; rr < 2; ++rr)
#pragma unroll
        for (int r = 0; r < RK; ++r) {
            acc[rr][r] += __shfl_xor(acc[rr][r], 32);
            acc[rr][r] += __shfl_xor(acc[rr][r], 16);
        }
    // red aliases smem[0..2303] (buf0: last read at c=14, fenced by that sync;
    // c=15 compute read buf1 only)
    __syncthreads();
    if (l < 16) {
#pragma unroll
        for (int rr = 0; rr < 2; ++rr)
#pragma unroll
            for (int q = 0; q < 4; ++q)
                *(float4*)&smem[(wv * 16 + l) * RST + rr * 16 + q * 4] =
                    make_float4(acc[rr][q * 4 + 0], acc[rr][q * 4 + 1],
                                acc[rr][q * 4 + 2], acc[rr][q * 4 + 3]);
    }
    __syncthreads();
    if (tid < ROWS * RK) {
        const int row = tid >> 4, r = tid & 15;
        const int ws = row >> 1, rr = row & 1;
        float s = 0.f;
#pragma unroll
        for (int lp = 0; lp < 16; ++lp)
            s += smem[(ws * 16 + lp) * RST + rr * 16 + r];
        tl[row * RK + r] = s;
    }
    __syncthreads();

    // ---- phase 2: out[8][4096] = t @ left^T + bias, 4 column chunks
#pragma unroll 1
    for (int oc = 0; oc < 4; ++oc) {
        const int o0 = oc * 1024 + tid * 4;
        float4 lf[4][4];
#pragma unroll
        for (int oo = 0; oo < 4; ++oo)
#pragma unroll
            for (int q = 0; q < 4; ++q)
                lf[oo][q] = *(const float4*)&lft[(size_t)(o0 + oo) * RK + q * 4];
        const float4 bv = *(const float4*)&bias[o0];
        const float  bvf[4] = {bv.x, bv.y, bv.z, bv.w};

#pragma unroll
        for (int rr = 0; rr < ROWS; ++rr) {
            float4 ts[4];
#pragma unroll
            for (int q = 0; q < 4; ++q)
                ts[q] = ((const float4*)tl)[rr * 4 + q];   // uniform -> broadcast

            float res[4];
#pragma unroll
            for (int oo = 0; oo < 4; ++oo) {
                float a = bvf[oo];
#pragma unroll
                for (int q = 0; q < 4; ++q) {
                    a += lf[oo][q].x * ts[q].x;
                    a += lf[oo][q].y * ts[q].y;
                    a += lf[oo][q].z * ts[q].z;
                    a += lf[oo][q].w * ts[q].w;
                }
                res[oo] = a;
            }
            *(float4*)&out[(size_t)(row0 + rr) * COUT + o0] =
                make_float4(res[0], res[1], res[2], res[3]);
        }
    }
}

extern "C" void kernel_launch(void* const* d_in, const int* in_sizes, int n_in,
                              void* d_out, int out_size, void* d_ws, size_t ws_size,
                              hipStream_t stream)
{
    const float* x    = (const float*)d_in[0];
    const float* lft  = (const float*)d_in[1];   // [COUT][RK]
    const float* rgt  = (const float*)d_in[2];   // [RK][CIN]
    const float* bias = (const float*)d_in[3];
    float*       out  = (float*)d_out;

    (void)d_ws; (void)ws_size;                   // workspace unused (no poison fill)

    fused<<<dim3(NT / ROWS), dim3(256), 0, stream>>>(x, rgt, lft, bias, out);
}

// Round 4
// 297.063 us; speedup vs baseline: 3.1062x; 1.2417x over previous
//
#include <hip/hip_runtime.h>

#define NT    8192   // tokens
#define CIN   4096   // in_channel
#define COUT  4096   // out_channel
#define RK    16     // rank
#define ROWS  8      // tokens per block -> grid 1024 = 4 blocks/CU
#define CHUNK 256    // k per staged chunk
#define NCHUNK (CIN / CHUNK)   // 16
#define RST   36     // red row stride (floats): bank = 4*l -> 2-way = free

// async global->LDS, 16B per lane: LDS dest = wave-uniform base + lane*16,
// global src = per-lane address. Our rgt staging layout is exactly linear in
// lane order, so this replaces the reg-prefetch+park path (-16 VGPR, no park
// VALU). Data is published by the vmcnt(0) drain at the next __syncthreads.
__device__ __forceinline__ void gload_lds16(const float* g, float* l)
{
    __builtin_amdgcn_global_load_lds(
        (const __attribute__((address_space(1))) void*)g,
        (__attribute__((address_space(3))) void*)l, 16, 0, 0);
}

// ---------------------------------------------------------------------------
// Fused out = (x @ right^T) @ left^T + bias. One kernel, no workspace.
// grid = 1024 (8-token groups), 256 threads (4 waves).
// Phase 1 (lane = k-column): per 256-k chunk, lane l owns k = l*4..l*4+3.
//   - x: global->reg only (zero reuse), coalesced, 1-chunk-ahead prefetch.
//   - rgt: LDS double-buffered [16][256] linear via global_load_lds;
//     rv read rs[r*256+l*4] = 64 lanes contiguous 1 KB -> conflict-free
//     (r3 verified: SQ_LDS_BANK_CONFLICT == 0).
//   k is 64-way lane-split: shfl_xor(32,16) + padded-LDS reduce -> t[8][16].
// Phase 2: two half-passes of lf[2][4] (32 regs, was 64) per column chunk;
//   thread -> outputs {o0, o0+1}, o0 = oc*1024 + h*512 + tid*2 so float2
//   stores stay fully contiguous per wave.
// VGPR target <=128: r3's 180 VGPR gave 2 blocks/CU (Occupancy 11%) and a
// pure latency-bound 214 us at 13% HBM. 4 blocks/CU is the whole game.
// NOTE: plain __launch_bounds__(256) — the (256,4) hint clamped to 64 VGPR
// and spilled 2.5 GB/launch (r2).
// ---------------------------------------------------------------------------
__global__ __launch_bounds__(256) void fused(const float* __restrict__ x,
                                             const float* __restrict__ rgt,
                                             const float* __restrict__ lft,
                                             const float* __restrict__ bias,
                                             float* __restrict__ out)
{
    __shared__ __align__(16) float smem[8192];     // [2][4096] rgt dbuf; red aliases [0..2303]
    __shared__ __align__(16) float tl[ROWS * RK];  // t[8][16]

    const int tid = threadIdx.x;
    const int wv  = tid >> 6;
    const int l   = tid & 63;
    const int row0 = blockIdx.x * ROWS;

    // wave owns token rows {wv*2, wv*2+1}; lane owns k-cols l*4..l*4+3 per chunk
    const float* xr0 = x + (size_t)(row0 + wv * 2)     * CIN + l * 4;
    const float* xr1 = x + (size_t)(row0 + wv * 2 + 1) * CIN + l * 4;

    float4 pfx[2][2];
    float  acc[2][RK];
#pragma unroll
    for (int r = 0; r < RK; ++r) { acc[0][r] = 0.f; acc[1][r] = 0.f; }

    // ---- prologue: stage chunk 0 into buf0 (async), x chunk 0 into regs
#pragma unroll
    for (int i = 0; i < 4; ++i)
        gload_lds16(&rgt[(size_t)(i * 4 + wv) * CIN + l * 4],
                    &smem[(i * 4 + wv) * CHUNK]);
    pfx[0][0] = *(const float4*)&xr0[0];
    pfx[0][1] = *(const float4*)&xr1[0];
    __syncthreads();   // vmcnt(0) drain publishes buf0

#pragma unroll 2
    for (int c = 0; c < NCHUNK; ++c) {
        const int cb = c & 1, nb = (c + 1) & 1;
        // issue next chunk at the TOP: full compute period in flight.
        // safe: all waves passed end-of-(c-1) barrier, so buf nb's readers
        // (iteration c-1 computed buf nb) are done.
        if (c + 1 < NCHUNK) {
            const int ko = (c + 1) * CHUNK;
#pragma unroll
            for (int i = 0; i < 4; ++i)
                gload_lds16(&rgt[(size_t)(i * 4 + wv) * CIN + ko + l * 4],
                            &smem[nb * 4096 + (i * 4 + wv) * CHUNK]);
            pfx[nb][0] = *(const float4*)&xr0[ko];
            pfx[nb][1] = *(const float4*)&xr1[ko];
        }
        // compute chunk c: 16 contiguous b128 reads + 128 fmac
        const float* rsb = &smem[cb * 4096];
        const float4 xv0 = pfx[cb][0], xv1 = pfx[cb][1];
#pragma unroll
        for (int r = 0; r < RK; ++r) {
            const float4 rv = *(const float4*)&rsb[r * CHUNK + l * 4];
            acc[0][r] += rv.x * xv0.x; acc[0][r] += rv.y * xv0.y;
            acc[0][r] += rv.z * xv0.z; acc[0][r] += rv.w * xv0.w;
            acc[1][r] += rv.x * xv1.x; acc[1][r] += rv.y * xv1.y;
            acc[1][r] += rv.z * xv1.z; acc[1][r] += rv.w * xv1.w;
        }
        if (c + 1 < NCHUNK) __syncthreads();   // publishes buf nb for iter c+1
    }

    // ---- k-reduce: 64 lanes -> 16 partials -> t[8][16]
#pragma unroll
    for (int rr = 0; rr < 2; ++rr)
#pragma unroll
        for (int r = 0; r < RK; ++r) {
            acc[rr][r] += __shfl_xor(acc[rr][r], 32);
            acc[rr][r] += __shfl_xor(acc[rr][r], 16);
        }
    // red aliases smem[0..2303] (buf0: last read at c=14, fenced by that
    // iteration's barrier; c=15 read buf1 only; no loads pending)
    __syncthreads();
    if (l < 16) {
#pragma unroll
        for (int rr = 0; rr < 2; ++rr)
#pragma unroll
            for (int q = 0; q < 4; ++q)
                *(float4*)&smem[(wv * 16 + l) * RST + rr * 16 + q * 4] =
                    make_float4(acc[rr][q * 4 + 0], acc[rr][q * 4 + 1],
                                acc[rr][q * 4 + 2], acc[rr][q * 4 + 3]);
    }
    __syncthreads();
    if (tid < ROWS * RK) {
        const int row = tid >> 4, r = tid & 15;
        const int ws = row >> 1, rr = row & 1;
        float s = 0.f;
#pragma unroll
        for (int lp = 0; lp < 16; ++lp)
            s += smem[(ws * 16 + lp) * RST + rr * 16 + r];
        tl[row * RK + r] = s;
    }
    __syncthreads();

    // ---- phase 2: out[8][4096] = t @ left^T + bias.
    // 4 column chunks x 2 half-passes; lf[2][4] = 32 regs peak.
#pragma unroll 1
    for (int oc = 0; oc < 4; ++oc) {
#pragma unroll 1
        for (int h = 0; h < 2; ++h) {
            const int o0 = oc * 1024 + h * 512 + tid * 2;
            float4 lf0[4], lf1[4];
#pragma unroll
            for (int q = 0; q < 4; ++q) {
                lf0[q] = *(const float4*)&lft[(size_t)o0 * RK + q * 4];
                lf1[q] = *(const float4*)&lft[(size_t)(o0 + 1) * RK + q * 4];
            }
            const float2 bv = *(const float2*)&bias[o0];

#pragma unroll
            for (int rr = 0; rr < ROWS; ++rr) {
                float4 ts[4];
#pragma unroll
                for (int q = 0; q < 4; ++q)
                    ts[q] = ((const float4*)tl)[rr * 4 + q];   // uniform -> broadcast

                float r0 = bv.x, r1 = bv.y;
#pragma unroll
                for (int q = 0; q < 4; ++q) {
                    r0 += lf0[q].x * ts[q].x; r0 += lf0[q].y * ts[q].y;
                    r0 += lf0[q].z * ts[q].z; r0 += lf0[q].w * ts[q].w;
                    r1 += lf1[q].x * ts[q].x; r1 += lf1[q].y * ts[q].y;
                    r1 += lf1[q].z * ts[q].z; r1 += lf1[q].w * ts[q].w;
                }
                *(float2*)&out[(size_t)(row0 + rr) * COUT + o0] =
                    make_float2(r0, r1);
            }
        }
    }
}

extern "C" void kernel_launch(void* const* d_in, const int* in_sizes, int n_in,
                              void* d_out, int out_size, void* d_ws, size_t ws_size,
                              hipStream_t stream)
{
    const float* x    = (const float*)d_in[0];
    const float* lft  = (const float*)d_in[1];   // [COUT][RK]
    const float* rgt  = (const float*)d_in[2];   // [RK][CIN]
    const float* bias = (const float*)d_in[3];
    float*       out  = (float*)d_out;

    (void)d_ws; (void)ws_size;                   // workspace unused

    fused<<<dim3(NT / ROWS), dim3(256), 0, stream>>>(x, rgt, lft, bias, out);
}